// Round 1
// baseline (1458.130 us; speedup 1.0000x reference)
//
#include <hip/hip_runtime.h>

#define N_NODES 100000
#define N_EDGES 600000
#define N_GRAPHS 64
#define BN_EPS 1e-5f

// ---------------------------------------------------------------------------
// Scatter-add: aggr[dst[e]][f] += x[src[e]][f], one thread per (edge, feat).
// d is a power of two (128 or 64) so lanes of a wave share one edge:
// src/dst loads broadcast, gather + atomic addresses are consecutive.
// ---------------------------------------------------------------------------
__global__ void scatter_add_kernel(const float* __restrict__ x,
                                   const int* __restrict__ src,
                                   const int* __restrict__ dst,
                                   float* __restrict__ aggr,
                                   long total, int d_log2) {
    long tid = (long)blockIdx.x * blockDim.x + threadIdx.x;
    if (tid >= total) return;
    int e = (int)(tid >> d_log2);
    int f = (int)(tid & ((1 << d_log2) - 1));
    int s = src[e];
    int t = dst[e];
    atomicAdd(&aggr[((long)t << d_log2) + f], x[((long)s << d_log2) + f]);
}

// ---------------------------------------------------------------------------
// GEMM1 + ReLU: hid[n][j] = relu(b1[j] + sum_k in[n][k] * w1[k][j]),
// one thread per (node, hidden). d_hid is always 64 -> j = tid & 63,
// so w1[k*64+j] is coalesced across lanes and in[n][k] broadcasts.
// ---------------------------------------------------------------------------
__global__ void gemm1_relu_kernel(const float* __restrict__ in,
                                  const float* __restrict__ w1,
                                  const float* __restrict__ b1,
                                  float* __restrict__ hid,
                                  int n_nodes, int d_in) {
    int tid = blockIdx.x * blockDim.x + threadIdx.x;
    if (tid >= n_nodes * 64) return;
    int n = tid >> 6;
    int j = tid & 63;
    const float* row = in + (long)n * d_in;
    float acc = b1[j];
    for (int k = 0; k < d_in; k += 4) {
        float4 a = *(const float4*)(row + k);
        acc = fmaf(a.x, w1[(k + 0) * 64 + j], acc);
        acc = fmaf(a.y, w1[(k + 1) * 64 + j], acc);
        acc = fmaf(a.z, w1[(k + 2) * 64 + j], acc);
        acc = fmaf(a.w, w1[(k + 3) * 64 + j], acc);
    }
    hid[tid] = fmaxf(acc, 0.0f);
}

// ---------------------------------------------------------------------------
// GEMM2 + bias + eval-BN + ReLU: one thread per (node, out channel).
// out[n][c] = relu( (b2[c] + sum_j hid[n][j]*w2[j][c] - m[c]) * s[c] + bb[c] )
// with s[c] = g[c] * rsqrt(v[c] + eps).
// ---------------------------------------------------------------------------
__global__ void gemm2_bn_relu_kernel(const float* __restrict__ hid,
                                     const float* __restrict__ w2,
                                     const float* __restrict__ b2,
                                     const float* __restrict__ bn_g,
                                     const float* __restrict__ bn_b,
                                     const float* __restrict__ bn_m,
                                     const float* __restrict__ bn_v,
                                     float* __restrict__ out,
                                     int n_nodes, int d_out) {
    int tid = blockIdx.x * blockDim.x + threadIdx.x;
    if (tid >= n_nodes * d_out) return;
    int n = tid / d_out;
    int c = tid - n * d_out;
    const float* hrow = hid + (long)n * 64;
    float acc = b2[c];
    for (int j = 0; j < 64; j += 4) {
        float4 h4 = *(const float4*)(hrow + j);
        acc = fmaf(h4.x, w2[(j + 0) * d_out + c], acc);
        acc = fmaf(h4.y, w2[(j + 1) * d_out + c], acc);
        acc = fmaf(h4.z, w2[(j + 2) * d_out + c], acc);
        acc = fmaf(h4.w, w2[(j + 3) * d_out + c], acc);
    }
    float s = bn_g[c] * rsqrtf(bn_v[c] + BN_EPS);
    float y = (acc - bn_m[c]) * s + bn_b[c];
    out[tid] = fmaxf(y, 0.0f);
}

// ---------------------------------------------------------------------------
// Mean-pool phase 1: per-block LDS accumulation over a contiguous node chunk
// (batch is sorted, so a chunk touches few graphs), then one global atomic
// per (graph, feat) per block. 128 threads; thread f owns feature f (f < 96).
// ---------------------------------------------------------------------------
#define POOL_CHUNK 256
__global__ void pool_kernel(const float* __restrict__ h,
                            const int* __restrict__ batch,
                            float* __restrict__ sums,
                            float* __restrict__ counts,
                            int n_nodes) {
    __shared__ float acc[N_GRAPHS * 96];
    __shared__ float cnt[N_GRAPHS];
    for (int i = threadIdx.x; i < N_GRAPHS * 96; i += blockDim.x) acc[i] = 0.0f;
    for (int i = threadIdx.x; i < N_GRAPHS; i += blockDim.x) cnt[i] = 0.0f;
    __syncthreads();
    int f = threadIdx.x;
    int start = blockIdx.x * POOL_CHUNK;
    int end = start + POOL_CHUNK;
    if (end > n_nodes) end = n_nodes;
    if (f < 96) {
        for (int n = start; n < end; ++n) {
            int g = batch[n];
            acc[g * 96 + f] += h[(long)n * 96 + f];
            if (f == 0) cnt[g] += 1.0f;
        }
    }
    __syncthreads();
    for (int i = threadIdx.x; i < N_GRAPHS * 96; i += blockDim.x)
        if (acc[i] != 0.0f) atomicAdd(&sums[i], acc[i]);
    for (int i = threadIdx.x; i < N_GRAPHS; i += blockDim.x)
        if (cnt[i] != 0.0f) atomicAdd(&counts[i], cnt[i]);
}

__global__ void finalize_kernel(const float* __restrict__ sums,
                                const float* __restrict__ counts,
                                float* __restrict__ out) {
    int i = blockIdx.x * blockDim.x + threadIdx.x;
    if (i >= N_GRAPHS * 96) return;
    int g = i / 96;
    out[i] = sums[i] / fmaxf(counts[g], 1.0f);
}

// ---------------------------------------------------------------------------
// Launch
// ---------------------------------------------------------------------------
static inline int cdiv_l(long a, int b) { return (int)((a + b - 1) / b); }

extern "C" void kernel_launch(void* const* d_in, const int* in_sizes, int n_in,
                              void* d_out, int out_size, void* d_ws, size_t ws_size,
                              hipStream_t stream) {
    const float* x    = (const float*)d_in[0];
    const int*   ei   = (const int*)d_in[1];
    const int*   src  = ei;
    const int*   dst  = ei + N_EDGES;
    const int*   batch = (const int*)d_in[2];

    // Per-layer params: w1, b1, w2, b2, bn_g, bn_b, bn_m, bn_v
    const float* P[3][8];
    int p = 3;
    for (int l = 0; l < 3; ++l)
        for (int q = 0; q < 8; ++q)
            P[l][q] = (const float*)d_in[p++];

    const int d_in_l[3]  = {128, 64, 64};
    const int d_out_l[3] = {64, 64, 96};
    const int d_log2_l[3] = {7, 6, 6};

    // Workspace layout (floats)
    float* ws     = (float*)d_ws;
    float* aggr   = ws;                        // 100000*128 = 12.8M
    float* hid    = aggr + (long)N_NODES * 128; // 100000*64  = 6.4M
    float* h0     = hid  + (long)N_NODES * 64;
    float* h1     = h0   + (long)N_NODES * 64;
    float* h2     = h1   + (long)N_NODES * 64;  // 100000*96
    float* sums   = h2   + (long)N_NODES * 96;
    float* counts = sums + N_GRAPHS * 96;

    const float* layer_in[3]  = {x, h0, h1};
    float*       layer_out[3] = {h0, h1, h2};

    const int B = 256;
    for (int l = 0; l < 3; ++l) {
        int di = d_in_l[l], dl2 = d_log2_l[l], dо = d_out_l[l];
        // aggr = x_in (self term), then scatter-add neighbor rows
        hipMemcpyAsync(aggr, layer_in[l], (size_t)N_NODES * di * sizeof(float),
                       hipMemcpyDeviceToDevice, stream);
        long total = (long)N_EDGES << dl2;
        scatter_add_kernel<<<cdiv_l(total, B), B, 0, stream>>>(
            layer_in[l], src, dst, aggr, total, dl2);
        // MLP: hid = relu(aggr @ w1 + b1)
        gemm1_relu_kernel<<<cdiv_l((long)N_NODES * 64, B), B, 0, stream>>>(
            aggr, P[l][0], P[l][1], hid, N_NODES, di);
        // out = relu(BN(hid @ w2 + b2))
        gemm2_bn_relu_kernel<<<cdiv_l((long)N_NODES * dо, B), B, 0, stream>>>(
            hid, P[l][2], P[l][3], P[l][4], P[l][5], P[l][6], P[l][7],
            layer_out[l], N_NODES, dо);
    }

    // Global mean pool
    hipMemsetAsync(sums, 0, (size_t)(N_GRAPHS * 96 + N_GRAPHS) * sizeof(float), stream);
    pool_kernel<<<cdiv_l(N_NODES, POOL_CHUNK), 128, 0, stream>>>(
        h2, batch, sums, counts, N_NODES);
    finalize_kernel<<<cdiv_l(N_GRAPHS * 96, B), B, 0, stream>>>(
        sums, counts, (float*)d_out);
}

// Round 2
// 1228.570 us; speedup vs baseline: 1.1869x; 1.1869x over previous
//
#include <hip/hip_runtime.h>

#define N_NODES 100000
#define N_EDGES 600000
#define N_GRAPHS 64
#define BN_EPS 1e-5f

// ===========================================================================
// CSR build (once per call): deg histogram -> scan -> cursor fill.
// Adjacency stored as src-node ids grouped by dst ("eids").
// ===========================================================================
__global__ void deg_hist_kernel(const int* __restrict__ dst,
                                int* __restrict__ deg, int n_edges) {
    int e = blockIdx.x * blockDim.x + threadIdx.x;
    if (e < n_edges) atomicAdd(&deg[dst[e]], 1);
}

// Per-1024-block exclusive scan; block totals to partials.
__global__ void scan1_kernel(const int* __restrict__ deg, int* __restrict__ excl,
                             int* __restrict__ partials, int n) {
    __shared__ int s[1024];
    int i = blockIdx.x * 1024 + threadIdx.x;
    int v = (i < n) ? deg[i] : 0;
    s[threadIdx.x] = v;
    __syncthreads();
    for (int off = 1; off < 1024; off <<= 1) {
        int t = (threadIdx.x >= (unsigned)off) ? s[threadIdx.x - off] : 0;
        __syncthreads();
        s[threadIdx.x] += t;
        __syncthreads();
    }
    if (i < n) excl[i] = s[threadIdx.x] - v;
    if (threadIdx.x == 1023) partials[blockIdx.x] = s[1023];
}

// Single-block exclusive scan of block partials (<=128 of them).
__global__ void scan2_kernel(int* partials, int nb) {
    __shared__ int s[128];
    int t = threadIdx.x;
    int v = (t < nb) ? partials[t] : 0;
    s[t] = v;
    __syncthreads();
    for (int off = 1; off < 128; off <<= 1) {
        int u = (t >= off) ? s[t - off] : 0;
        __syncthreads();
        s[t] += u;
        __syncthreads();
    }
    if (t < nb) partials[t] = s[t] - v;
}

__global__ void scan3_kernel(int* __restrict__ rowptr, const int* __restrict__ partials,
                             int n, int total) {
    int i = blockIdx.x * blockDim.x + threadIdx.x;
    if (i < n) rowptr[i] += partials[i >> 10];
    else if (i == n) rowptr[n] = total;
}

__global__ void csr_fill_kernel(const int* __restrict__ src, const int* __restrict__ dst,
                                const int* __restrict__ rowptr, int* __restrict__ cursor,
                                int* __restrict__ eids, int n_edges) {
    int e = blockIdx.x * blockDim.x + threadIdx.x;
    if (e >= n_edges) return;
    int t = dst[e];
    int pos = rowptr[t] + atomicAdd(&cursor[t], 1);
    eids[pos] = src[e];
}

// ===========================================================================
// Gather aggregation: aggr[n][f] = x[n][f] + sum_{s in adj(n)} x[s][f].
// One lane per feature; D=64 -> one wave per node (no divergence).
// eids[i] broadcasts within the group; x[s] rows are coalesced.
// ===========================================================================
template <int D>
__global__ void gather_aggr_kernel(const float* __restrict__ x,
                                   const int* __restrict__ rowptr,
                                   const int* __restrict__ eids,
                                   float* __restrict__ aggr, int n_nodes) {
    int node = blockIdx.x * (256 / D) + (int)(threadIdx.x / D);
    if (node >= n_nodes) return;
    int f = threadIdx.x & (D - 1);
    float acc = x[(long)node * D + f];
    int b = rowptr[node], e = rowptr[node + 1];
    for (int i = b; i < e; ++i) {
        int s = eids[i];
        acc += x[(long)s * D + f];
    }
    aggr[(long)node * D + f] = acc;
}

// ===========================================================================
// GEMM1 + ReLU: one thread per (node, hidden j). j = tid & 63 so w1 reads are
// coalesced, activation row broadcasts across the 64-lane group (L1 hit).
// ===========================================================================
__global__ void gemm1_relu_kernel(const float* __restrict__ in,
                                  const float* __restrict__ w1,
                                  const float* __restrict__ b1,
                                  float* __restrict__ hid,
                                  int n_nodes, int d_in) {
    int tid = blockIdx.x * blockDim.x + threadIdx.x;
    if (tid >= n_nodes * 64) return;
    int n = tid >> 6;
    int j = tid & 63;
    const float* row = in + (long)n * d_in;
    float acc = b1[j];
    for (int k = 0; k < d_in; k += 4) {
        float4 a = *(const float4*)(row + k);
        acc = fmaf(a.x, w1[(k + 0) * 64 + j], acc);
        acc = fmaf(a.y, w1[(k + 1) * 64 + j], acc);
        acc = fmaf(a.z, w1[(k + 2) * 64 + j], acc);
        acc = fmaf(a.w, w1[(k + 3) * 64 + j], acc);
    }
    hid[tid] = fmaxf(acc, 0.0f);
}

// ===========================================================================
// GEMM2 + bias + eval-BN + ReLU: one thread per (node, out channel).
// ===========================================================================
__global__ void gemm2_bn_relu_kernel(const float* __restrict__ hid,
                                     const float* __restrict__ w2,
                                     const float* __restrict__ b2,
                                     const float* __restrict__ bn_g,
                                     const float* __restrict__ bn_b,
                                     const float* __restrict__ bn_m,
                                     const float* __restrict__ bn_v,
                                     float* __restrict__ out,
                                     int n_nodes, int d_out) {
    int tid = blockIdx.x * blockDim.x + threadIdx.x;
    if (tid >= n_nodes * d_out) return;
    int n = tid / d_out;
    int c = tid - n * d_out;
    const float* hrow = hid + (long)n * 64;
    float acc = b2[c];
    for (int j = 0; j < 64; j += 4) {
        float4 h4 = *(const float4*)(hrow + j);
        acc = fmaf(h4.x, w2[(j + 0) * d_out + c], acc);
        acc = fmaf(h4.y, w2[(j + 1) * d_out + c], acc);
        acc = fmaf(h4.z, w2[(j + 2) * d_out + c], acc);
        acc = fmaf(h4.w, w2[(j + 3) * d_out + c], acc);
    }
    float s = bn_g[c] * rsqrtf(bn_v[c] + BN_EPS);
    float y = (acc - bn_m[c]) * s + bn_b[c];
    out[tid] = fmaxf(y, 0.0f);
}

// ===========================================================================
// Mean-pool: per-block LDS accumulation over a contiguous node chunk (batch
// is sorted), one global atomic per (graph, feat) per block.
// ===========================================================================
#define POOL_CHUNK 256
__global__ void pool_kernel(const float* __restrict__ h,
                            const int* __restrict__ batch,
                            float* __restrict__ sums,
                            float* __restrict__ counts,
                            int n_nodes) {
    __shared__ float acc[N_GRAPHS * 96];
    __shared__ float cnt[N_GRAPHS];
    for (int i = threadIdx.x; i < N_GRAPHS * 96; i += blockDim.x) acc[i] = 0.0f;
    for (int i = threadIdx.x; i < N_GRAPHS; i += blockDim.x) cnt[i] = 0.0f;
    __syncthreads();
    int f = threadIdx.x;
    int start = blockIdx.x * POOL_CHUNK;
    int end = start + POOL_CHUNK;
    if (end > n_nodes) end = n_nodes;
    if (f < 96) {
        for (int n = start; n < end; ++n) {
            int g = batch[n];
            acc[g * 96 + f] += h[(long)n * 96 + f];
            if (f == 0) cnt[g] += 1.0f;
        }
    }
    __syncthreads();
    for (int i = threadIdx.x; i < N_GRAPHS * 96; i += blockDim.x)
        if (acc[i] != 0.0f) atomicAdd(&sums[i], acc[i]);
    for (int i = threadIdx.x; i < N_GRAPHS; i += blockDim.x)
        if (cnt[i] != 0.0f) atomicAdd(&counts[i], cnt[i]);
}

__global__ void finalize_kernel(const float* __restrict__ sums,
                                const float* __restrict__ counts,
                                float* __restrict__ out) {
    int i = blockIdx.x * blockDim.x + threadIdx.x;
    if (i >= N_GRAPHS * 96) return;
    int g = i / 96;
    out[i] = sums[i] / fmaxf(counts[g], 1.0f);
}

// ---------------------------------------------------------------------------
static inline int cdiv_l(long a, int b) { return (int)((a + b - 1) / b); }

extern "C" void kernel_launch(void* const* d_in, const int* in_sizes, int n_in,
                              void* d_out, int out_size, void* d_ws, size_t ws_size,
                              hipStream_t stream) {
    const float* x     = (const float*)d_in[0];
    const int*   ei    = (const int*)d_in[1];
    const int*   src   = ei;
    const int*   dst   = ei + N_EDGES;
    const int*   batch = (const int*)d_in[2];

    const float* P[3][8];
    int p = 3;
    for (int l = 0; l < 3; ++l)
        for (int q = 0; q < 8; ++q)
            P[l][q] = (const float*)d_in[p++];

    // Workspace layout
    float* ws     = (float*)d_ws;
    float* aggr   = ws;                         // 100000*128
    float* hid    = aggr + (long)N_NODES * 128; // 100000*64
    float* hA     = hid + (long)N_NODES * 64;   // 100000*96 (max width)
    float* hB     = hA + (long)N_NODES * 96;    // 100000*96
    float* sums   = hB + (long)N_NODES * 96;    // 6144
    float* counts = sums + N_GRAPHS * 96;       // 64
    int* deg      = (int*)(counts + N_GRAPHS);  // 100000
    int* cursor   = deg + N_NODES;              // 100000
    int* partials = cursor + N_NODES;           // 128
    int* rowptr   = partials + 128;             // 100001
    int* eids     = rowptr + (N_NODES + 1);     // 600000

    const int B = 256;

    // ---- CSR build ----
    hipMemsetAsync(deg, 0, (size_t)(2 * N_NODES + 128) * sizeof(int), stream);
    deg_hist_kernel<<<cdiv_l(N_EDGES, B), B, 0, stream>>>(dst, deg, N_EDGES);
    int nblk = cdiv_l(N_NODES, 1024);  // 98
    scan1_kernel<<<nblk, 1024, 0, stream>>>(deg, rowptr, partials, N_NODES);
    scan2_kernel<<<1, 128, 0, stream>>>(partials, nblk);
    scan3_kernel<<<cdiv_l(N_NODES + 1, B), B, 0, stream>>>(rowptr, partials, N_NODES, N_EDGES);
    csr_fill_kernel<<<cdiv_l(N_EDGES, B), B, 0, stream>>>(src, dst, rowptr, cursor, eids, N_EDGES);

    // ---- 3 GIN layers ----
    const float* in0 = x;
    // layer 0: d_in=128 -> out hA (64)
    gather_aggr_kernel<128><<<cdiv_l((long)N_NODES * 128, B), B, 0, stream>>>(
        in0, rowptr, eids, aggr, N_NODES);
    gemm1_relu_kernel<<<cdiv_l((long)N_NODES * 64, B), B, 0, stream>>>(
        aggr, P[0][0], P[0][1], hid, N_NODES, 128);
    gemm2_bn_relu_kernel<<<cdiv_l((long)N_NODES * 64, B), B, 0, stream>>>(
        hid, P[0][2], P[0][3], P[0][4], P[0][5], P[0][6], P[0][7], hA, N_NODES, 64);
    // layer 1: hA (64) -> hB (64)
    gather_aggr_kernel<64><<<cdiv_l((long)N_NODES * 64, B), B, 0, stream>>>(
        hA, rowptr, eids, aggr, N_NODES);
    gemm1_relu_kernel<<<cdiv_l((long)N_NODES * 64, B), B, 0, stream>>>(
        aggr, P[1][0], P[1][1], hid, N_NODES, 64);
    gemm2_bn_relu_kernel<<<cdiv_l((long)N_NODES * 64, B), B, 0, stream>>>(
        hid, P[1][2], P[1][3], P[1][4], P[1][5], P[1][6], P[1][7], hB, N_NODES, 64);
    // layer 2: hB (64) -> hA (96)
    gather_aggr_kernel<64><<<cdiv_l((long)N_NODES * 64, B), B, 0, stream>>>(
        hB, rowptr, eids, aggr, N_NODES);
    gemm1_relu_kernel<<<cdiv_l((long)N_NODES * 64, B), B, 0, stream>>>(
        aggr, P[2][0], P[2][1], hid, N_NODES, 64);
    gemm2_bn_relu_kernel<<<cdiv_l((long)N_NODES * 96, B), B, 0, stream>>>(
        hid, P[2][2], P[2][3], P[2][4], P[2][5], P[2][6], P[2][7], hA, N_NODES, 96);

    // ---- Global mean pool ----
    hipMemsetAsync(sums, 0, (size_t)(N_GRAPHS * 96 + N_GRAPHS) * sizeof(float), stream);
    pool_kernel<<<cdiv_l(N_NODES, POOL_CHUNK), 128, 0, stream>>>(
        hA, batch, sums, counts, N_NODES);
    finalize_kernel<<<cdiv_l(N_GRAPHS * 96, B), B, 0, stream>>>(
        sums, counts, (float*)d_out);
}

// Round 3
// 710.755 us; speedup vs baseline: 2.0515x; 1.7285x over previous
//
#include <hip/hip_runtime.h>

#define N_NODES 100000
#define N_GRAPHS 64
#define N_EDGES 600000
#define BN_EPS 1e-5f

// ===========================================================================
// CSR build: deg histogram -> scan -> cursor fill. (~40 us total)
// ===========================================================================
__global__ void deg_hist_kernel(const int* __restrict__ dst,
                                int* __restrict__ deg, int n_edges) {
    int e = blockIdx.x * blockDim.x + threadIdx.x;
    if (e < n_edges) atomicAdd(&deg[dst[e]], 1);
}

__global__ void scan1_kernel(const int* __restrict__ deg, int* __restrict__ excl,
                             int* __restrict__ partials, int n) {
    __shared__ int s[1024];
    int i = blockIdx.x * 1024 + threadIdx.x;
    int v = (i < n) ? deg[i] : 0;
    s[threadIdx.x] = v;
    __syncthreads();
    for (int off = 1; off < 1024; off <<= 1) {
        int t = (threadIdx.x >= (unsigned)off) ? s[threadIdx.x - off] : 0;
        __syncthreads();
        s[threadIdx.x] += t;
        __syncthreads();
    }
    if (i < n) excl[i] = s[threadIdx.x] - v;
    if (threadIdx.x == 1023) partials[blockIdx.x] = s[1023];
}

__global__ void scan2_kernel(int* partials, int nb) {
    __shared__ int s[128];
    int t = threadIdx.x;
    int v = (t < nb) ? partials[t] : 0;
    s[t] = v;
    __syncthreads();
    for (int off = 1; off < 128; off <<= 1) {
        int u = (t >= off) ? s[t - off] : 0;
        __syncthreads();
        s[t] += u;
        __syncthreads();
    }
    if (t < nb) partials[t] = s[t] - v;
}

__global__ void scan3_kernel(int* __restrict__ rowptr, const int* __restrict__ partials,
                             int n, int total) {
    int i = blockIdx.x * blockDim.x + threadIdx.x;
    if (i < n) rowptr[i] += partials[i >> 10];
    else if (i == n) rowptr[n] = total;
}

__global__ void csr_fill_kernel(const int* __restrict__ src, const int* __restrict__ dst,
                                const int* __restrict__ rowptr, int* __restrict__ cursor,
                                int* __restrict__ eids, int n_edges) {
    int e = blockIdx.x * blockDim.x + threadIdx.x;
    if (e >= n_edges) return;
    int t = dst[e];
    int pos = rowptr[t] + atomicAdd(&cursor[t], 1);
    eids[pos] = src[e];
}

// ===========================================================================
// Gather aggregation: aggr[n][f] = x[n][f] + sum_{s in adj(n)} x[s][f].
// ===========================================================================
template <int D>
__global__ void gather_aggr_kernel(const float* __restrict__ x,
                                   const int* __restrict__ rowptr,
                                   const int* __restrict__ eids,
                                   float* __restrict__ aggr, int n_nodes) {
    int node = blockIdx.x * (256 / D) + (int)(threadIdx.x / D);
    if (node >= n_nodes) return;
    int f = threadIdx.x & (D - 1);
    float acc = x[(long)node * D + f];
    int b = rowptr[node], e = rowptr[node + 1];
    for (int i = b; i < e; ++i) {
        int s = eids[i];
        acc += x[(long)s * D + f];
    }
    aggr[(long)node * D + f] = acc;
}

// ===========================================================================
// Prep (once per layer): transpose w1 -> w1T[j][k]; fold BN scale into
// w2sT[c][j] = w2[j][c]*s[c]; bias2[c] = (b2[c]-m[c])*s[c]+bb[c].
// ===========================================================================
__global__ void prep_kernel(const float* __restrict__ w1, const float* __restrict__ w2,
                            const float* __restrict__ b2, const float* __restrict__ g,
                            const float* __restrict__ bb, const float* __restrict__ m,
                            const float* __restrict__ v,
                            float* __restrict__ w1T, float* __restrict__ w2sT,
                            float* __restrict__ bias2, int DIN, int DOUT) {
    int i = blockIdx.x * blockDim.x + threadIdx.x;
    if (i < 64 * DIN) {
        int j = i / DIN, k = i % DIN;
        w1T[i] = w1[k * 64 + j];
    }
    int i2 = i - 64 * DIN;
    if (i2 >= 0 && i2 < DOUT * 64) {
        int c = i2 / 64, j = i2 % 64;
        float s = g[c] * rsqrtf(v[c] + BN_EPS);
        w2sT[i2] = w2[j * DOUT + c] * s;
    }
    int i3 = i2 - DOUT * 64;
    if (i3 >= 0 && i3 < DOUT) {
        float s = g[i3] * rsqrtf(v[i3] + BN_EPS);
        bias2[i3] = (b2[i3] - m[i3]) * s + bb[i3];
    }
}

// ===========================================================================
// Fused MLP: out = relu( BNfold( relu(aggr@w1 + b1) @ w2s ) + bias2 )
// 64-node tile per block, 256 threads. Phase1: 4 nodes x 4 j per thread.
// Phase2: 4 nodes x CPT channels per thread (CPT = DOUT/16 = 4 or 6).
// Weights in LDS with XOR swizzle (k4 ^ (rowgroup&7)) -> <=2-way conflicts.
// aT/hid padded +4 floats -> row-groups land 16 banks apart (2-way, free).
// ===========================================================================
__device__ __forceinline__ void fma4(float& acc, const float4 a, const float4 w) {
    acc = fmaf(a.x, w.x, acc);
    acc = fmaf(a.y, w.y, acc);
    acc = fmaf(a.z, w.z, acc);
    acc = fmaf(a.w, w.w, acc);
}

template <int DIN, int DOUT>
__global__ __launch_bounds__(256)
void fused_mlp_kernel(const float* __restrict__ aggr,
                      const float* __restrict__ w1T,
                      const float* __restrict__ b1,
                      const float* __restrict__ w2sT,
                      const float* __restrict__ bias2,
                      float* __restrict__ out, int n_nodes) {
    constexpr int SA = DIN + 4;
    constexpr int SH = 64 + 4;
    constexpr int CPT = DOUT / 16;  // 4 or 6
    __shared__ float aT[64 * SA];
    __shared__ float w1s[64 * DIN];
    __shared__ float hid[64 * SH];
    __shared__ float w2s[DOUT * 64];

    const int tid = threadIdx.x;
    const long base = (long)blockIdx.x * 64;

    // ---- stage A-tile and weights (A rows beyond n_nodes read junk inside ws
    //      padding; their results are never stored) ----
    {
        const float4* ga = (const float4*)(aggr + base * DIN);
        for (int i4 = tid; i4 < 16 * DIN; i4 += 256) {
            int row = i4 / (DIN / 4), k4 = i4 % (DIN / 4);
            *(float4*)&aT[row * SA + k4 * 4] = ga[i4];
        }
        const float4* gw1 = (const float4*)w1T;
        for (int i4 = tid; i4 < 16 * DIN; i4 += 256) {
            int row = i4 / (DIN / 4), k4 = i4 % (DIN / 4);
            *(float4*)&w1s[row * DIN + ((k4 ^ ((row >> 2) & 7)) << 2)] = gw1[i4];
        }
        const float4* gw2 = (const float4*)w2sT;
        for (int i4 = tid; i4 < DOUT * 16; i4 += 256) {
            int row = i4 >> 4, k4 = i4 & 15;
            *(float4*)&w2s[row * 64 + ((k4 ^ ((row / CPT) & 7)) << 2)] = gw2[i4];
        }
    }
    __syncthreads();

    // ---- phase 1: hid[64][64] = relu(aT @ w1 + b1) ----
    {
        const int jg = tid & 15, ng = tid >> 4;
        const float* ap = &aT[(ng * 4) * SA];
        const float* wp = &w1s[(jg * 4) * DIN];
        const int xw = jg & 7;
        float acc[4][4] = {};
        #pragma unroll 4
        for (int k4 = 0; k4 < DIN / 4; ++k4) {
            const int ko = (k4 ^ xw) << 2;
            float4 w0 = *(const float4*)&wp[0 * DIN + ko];
            float4 w1v = *(const float4*)&wp[1 * DIN + ko];
            float4 w2v = *(const float4*)&wp[2 * DIN + ko];
            float4 w3v = *(const float4*)&wp[3 * DIN + ko];
            #pragma unroll
            for (int i = 0; i < 4; ++i) {
                float4 a = *(const float4*)&ap[i * SA + k4 * 4];
                fma4(acc[i][0], a, w0);
                fma4(acc[i][1], a, w1v);
                fma4(acc[i][2], a, w2v);
                fma4(acc[i][3], a, w3v);
            }
        }
        float4 bv = *(const float4*)&b1[jg * 4];
        #pragma unroll
        for (int i = 0; i < 4; ++i) {
            float4 hv;
            hv.x = fmaxf(acc[i][0] + bv.x, 0.0f);
            hv.y = fmaxf(acc[i][1] + bv.y, 0.0f);
            hv.z = fmaxf(acc[i][2] + bv.z, 0.0f);
            hv.w = fmaxf(acc[i][3] + bv.w, 0.0f);
            *(float4*)&hid[(ng * 4 + i) * SH + jg * 4] = hv;
        }
    }
    __syncthreads();

    // ---- phase 2: out[64][DOUT] = relu(hid @ w2s + bias2) ----
    {
        const int cg = tid & 15, ng = tid >> 4;
        const float* hp = &hid[(ng * 4) * SH];
        const float* wp = &w2s[(cg * CPT) * 64];
        const int xw = cg & 7;
        float acc[4][CPT] = {};
        #pragma unroll 4
        for (int k4 = 0; k4 < 16; ++k4) {
            const int ko = (k4 ^ xw) << 2;
            float4 wv[CPT];
            #pragma unroll
            for (int c = 0; c < CPT; ++c) wv[c] = *(const float4*)&wp[c * 64 + ko];
            #pragma unroll
            for (int i = 0; i < 4; ++i) {
                float4 h = *(const float4*)&hp[i * SH + k4 * 4];
                #pragma unroll
                for (int c = 0; c < CPT; ++c) fma4(acc[i][c], h, wv[c]);
            }
        }
        float bv[CPT];
        #pragma unroll
        for (int c = 0; c < CPT; ++c) bv[c] = bias2[cg * CPT + c];
        #pragma unroll
        for (int i = 0; i < 4; ++i) {
            long n = base + ng * 4 + i;
            if (n < n_nodes) {
                float* op = out + n * DOUT + cg * CPT;
                #pragma unroll
                for (int c = 0; c < CPT; ++c) op[c] = fmaxf(acc[i][c] + bv[c], 0.0f);
            }
        }
    }
}

// ===========================================================================
// Mean-pool + finalize
// ===========================================================================
#define POOL_CHUNK 256
__global__ void pool_kernel(const float* __restrict__ h,
                            const int* __restrict__ batch,
                            float* __restrict__ sums,
                            float* __restrict__ counts,
                            int n_nodes) {
    __shared__ float acc[N_GRAPHS * 96];
    __shared__ float cnt[N_GRAPHS];
    for (int i = threadIdx.x; i < N_GRAPHS * 96; i += blockDim.x) acc[i] = 0.0f;
    for (int i = threadIdx.x; i < N_GRAPHS; i += blockDim.x) cnt[i] = 0.0f;
    __syncthreads();
    int f = threadIdx.x;
    int start = blockIdx.x * POOL_CHUNK;
    int end = start + POOL_CHUNK;
    if (end > n_nodes) end = n_nodes;
    if (f < 96) {
        for (int n = start; n < end; ++n) {
            int g = batch[n];
            acc[g * 96 + f] += h[(long)n * 96 + f];
            if (f == 0) cnt[g] += 1.0f;
        }
    }
    __syncthreads();
    for (int i = threadIdx.x; i < N_GRAPHS * 96; i += blockDim.x)
        if (acc[i] != 0.0f) atomicAdd(&sums[i], acc[i]);
    for (int i = threadIdx.x; i < N_GRAPHS; i += blockDim.x)
        if (cnt[i] != 0.0f) atomicAdd(&counts[i], cnt[i]);
}

__global__ void finalize_kernel(const float* __restrict__ sums,
                                const float* __restrict__ counts,
                                float* __restrict__ out) {
    int i = blockIdx.x * blockDim.x + threadIdx.x;
    if (i >= N_GRAPHS * 96) return;
    int g = i / 96;
    out[i] = sums[i] / fmaxf(counts[g], 1.0f);
}

// ---------------------------------------------------------------------------
static inline int cdiv_l(long a, int b) { return (int)((a + b - 1) / b); }

extern "C" void kernel_launch(void* const* d_in, const int* in_sizes, int n_in,
                              void* d_out, int out_size, void* d_ws, size_t ws_size,
                              hipStream_t stream) {
    const float* x     = (const float*)d_in[0];
    const int*   ei    = (const int*)d_in[1];
    const int*   src   = ei;
    const int*   dst   = ei + N_EDGES;
    const int*   batch = (const int*)d_in[2];

    const float* P[3][8];
    int p = 3;
    for (int l = 0; l < 3; ++l)
        for (int q = 0; q < 8; ++q)
            P[l][q] = (const float*)d_in[p++];

    // Workspace layout (row counts padded +64 so the last tile's unguarded
    // A-tile staging reads stay inside the workspace).
    const long NP = N_NODES + 64;
    float* ws     = (float*)d_ws;
    float* aggr   = ws;                    // NP*128
    float* hA     = aggr + NP * 128;       // NP*96
    float* hB     = hA + NP * 96;          // NP*96
    float* wbuf   = hB + NP * 96;          // 3*(64*128 + 96*64 + 96)
    float* w1T[3], *w2sT[3], *bias2[3];
    {
        float* q = wbuf;
        for (int l = 0; l < 3; ++l) {
            w1T[l] = q;   q += 64 * 128;
            w2sT[l] = q;  q += 96 * 64;
            bias2[l] = q; q += 96;
        }
        float* sums   = q;                 // 6144
        float* counts = sums + N_GRAPHS * 96;
        int* deg      = (int*)(counts + N_GRAPHS);
        int* cursor   = deg + N_NODES;
        int* partials = cursor + N_NODES;
        int* rowptr   = partials + 128;
        int* eids     = rowptr + (N_NODES + 1);

        const int B = 256;
        const int DIN[3]  = {128, 64, 64};
        const int DOUT[3] = {64, 64, 96};

        // ---- prep (weights transpose + BN fold), independent of CSR ----
        for (int l = 0; l < 3; ++l) {
            int tot = 64 * DIN[l] + 64 * DOUT[l] + DOUT[l];
            prep_kernel<<<cdiv_l(tot, B), B, 0, stream>>>(
                P[l][0], P[l][2], P[l][3], P[l][4], P[l][5], P[l][6], P[l][7],
                w1T[l], w2sT[l], bias2[l], DIN[l], DOUT[l]);
        }

        // ---- CSR build ----
        hipMemsetAsync(deg, 0, (size_t)(2 * N_NODES + 128) * sizeof(int), stream);
        deg_hist_kernel<<<cdiv_l(N_EDGES, B), B, 0, stream>>>(dst, deg, N_EDGES);
        int nblk = cdiv_l(N_NODES, 1024);
        scan1_kernel<<<nblk, 1024, 0, stream>>>(deg, rowptr, partials, N_NODES);
        scan2_kernel<<<1, 128, 0, stream>>>(partials, nblk);
        scan3_kernel<<<cdiv_l(N_NODES + 1, B), B, 0, stream>>>(rowptr, partials, N_NODES, N_EDGES);
        csr_fill_kernel<<<cdiv_l(N_EDGES, B), B, 0, stream>>>(src, dst, rowptr, cursor, eids, N_EDGES);

        int ntiles = cdiv_l(N_NODES, 64);

        // ---- layer 0: x(128) -> hA(64) ----
        gather_aggr_kernel<128><<<cdiv_l((long)N_NODES * 128, B), B, 0, stream>>>(
            x, rowptr, eids, aggr, N_NODES);
        fused_mlp_kernel<128, 64><<<ntiles, 256, 0, stream>>>(
            aggr, w1T[0], P[0][1], w2sT[0], bias2[0], hA, N_NODES);
        // ---- layer 1: hA(64) -> hB(64) ----
        gather_aggr_kernel<64><<<cdiv_l((long)N_NODES * 64, B), B, 0, stream>>>(
            hA, rowptr, eids, aggr, N_NODES);
        fused_mlp_kernel<64, 64><<<ntiles, 256, 0, stream>>>(
            aggr, w1T[1], P[1][1], w2sT[1], bias2[1], hB, N_NODES);
        // ---- layer 2: hB(64) -> hA(96) ----
        gather_aggr_kernel<64><<<cdiv_l((long)N_NODES * 64, B), B, 0, stream>>>(
            hB, rowptr, eids, aggr, N_NODES);
        fused_mlp_kernel<64, 96><<<ntiles, 256, 0, stream>>>(
            aggr, w1T[2], P[2][1], w2sT[2], bias2[2], hA, N_NODES);

        // ---- global mean pool ----
        hipMemsetAsync(sums, 0, (size_t)(N_GRAPHS * 96 + N_GRAPHS) * sizeof(float), stream);
        pool_kernel<<<cdiv_l(N_NODES, POOL_CHUNK), 128, 0, stream>>>(
            hA, batch, sums, counts, N_NODES);
        finalize_kernel<<<cdiv_l(N_GRAPHS * 96, B), B, 0, stream>>>(
            sums, counts, (float*)d_out);
    }
}

// Round 4
// 516.805 us; speedup vs baseline: 2.8214x; 1.3753x over previous
//
#include <hip/hip_runtime.h>

#define N_NODES 100000
#define N_GRAPHS 64
#define N_EDGES 600000
#define BN_EPS 1e-5f

// ===========================================================================
// CSR build: deg histogram -> scan -> cursor fill.
// ===========================================================================
__global__ void deg_hist_kernel(const int* __restrict__ dst,
                                int* __restrict__ deg, int n_edges) {
    int e = blockIdx.x * blockDim.x + threadIdx.x;
    if (e < n_edges) atomicAdd(&deg[dst[e]], 1);
}

__global__ void scan1_kernel(const int* __restrict__ deg, int* __restrict__ excl,
                             int* __restrict__ partials, int n) {
    __shared__ int s[1024];
    int i = blockIdx.x * 1024 + threadIdx.x;
    int v = (i < n) ? deg[i] : 0;
    s[threadIdx.x] = v;
    __syncthreads();
    for (int off = 1; off < 1024; off <<= 1) {
        int t = (threadIdx.x >= (unsigned)off) ? s[threadIdx.x - off] : 0;
        __syncthreads();
        s[threadIdx.x] += t;
        __syncthreads();
    }
    if (i < n) excl[i] = s[threadIdx.x] - v;
    if (threadIdx.x == 1023) partials[blockIdx.x] = s[1023];
}

__global__ void scan2_kernel(int* partials, int nb) {
    __shared__ int s[128];
    int t = threadIdx.x;
    int v = (t < nb) ? partials[t] : 0;
    s[t] = v;
    __syncthreads();
    for (int off = 1; off < 128; off <<= 1) {
        int u = (t >= off) ? s[t - off] : 0;
        __syncthreads();
        s[t] += u;
        __syncthreads();
    }
    if (t < nb) partials[t] = s[t] - v;
}

__global__ void scan3_kernel(int* __restrict__ rowptr, const int* __restrict__ partials,
                             int n, int total) {
    int i = blockIdx.x * blockDim.x + threadIdx.x;
    if (i < n) rowptr[i] += partials[i >> 10];
    else if (i == n) rowptr[n] = total;
}

__global__ void csr_fill_kernel(const int* __restrict__ src, const int* __restrict__ dst,
                                const int* __restrict__ rowptr, int* __restrict__ cursor,
                                int* __restrict__ eids, int n_edges) {
    int e = blockIdx.x * blockDim.x + threadIdx.x;
    if (e >= n_edges) return;
    int t = dst[e];
    int pos = rowptr[t] + atomicAdd(&cursor[t], 1);
    eids[pos] = src[e];
}

// ===========================================================================
// Prep per layer: w1T[j][k] = w1[k][j]; w2sT[c][j] = w2[j][c]*s[c];
// bias2[c] = (b2[c]-m[c])*s[c]+bb[c].
// ===========================================================================
__global__ void prep_kernel(const float* __restrict__ w1, const float* __restrict__ w2,
                            const float* __restrict__ b2, const float* __restrict__ g,
                            const float* __restrict__ bb, const float* __restrict__ m,
                            const float* __restrict__ v,
                            float* __restrict__ w1T, float* __restrict__ w2sT,
                            float* __restrict__ bias2, int DIN, int DOUT) {
    int i = blockIdx.x * blockDim.x + threadIdx.x;
    if (i < 64 * DIN) {
        int j = i / DIN, k = i % DIN;
        w1T[i] = w1[k * 64 + j];
    }
    int i2 = i - 64 * DIN;
    if (i2 >= 0 && i2 < DOUT * 64) {
        int c = i2 / 64, j = i2 % 64;
        float s = g[c] * rsqrtf(v[c] + BN_EPS);
        w2sT[i2] = w2[j * DOUT + c] * s;
    }
    int i3 = i2 - DOUT * 64;
    if (i3 >= 0 && i3 < DOUT) {
        float s = g[i3] * rsqrtf(v[i3] + BN_EPS);
        bias2[i3] = (b2[i3] - m[i3]) * s + bb[i3];
    }
}

// ===========================================================================
// pre-GEMM: y = x @ W1_0  (100k x 128 -> 100k x 64). 64-node tile per block.
// ===========================================================================
__global__ __launch_bounds__(256)
void pre_gemm_kernel(const float* __restrict__ x, const float* __restrict__ w1T,
                     float* __restrict__ y, int n_nodes) {
    constexpr int SA = 132;
    __shared__ float xT[64 * SA];
    __shared__ float w1s[64 * 128];
    const int tid = threadIdx.x;
    const long base = (long)blockIdx.x * 64;

    for (int i4 = tid; i4 < 16 * 128; i4 += 256) {
        int row = i4 >> 5, k4 = i4 & 31;
        long r = base + row;
        if (r >= n_nodes) r = n_nodes - 1;  // clamp: x is an input, no padding
        *(float4*)&xT[row * SA + k4 * 4] = ((const float4*)x)[r * 32 + k4];
    }
    const float4* gw1 = (const float4*)w1T;
    for (int i4 = tid; i4 < 16 * 128; i4 += 256) {
        int row = i4 >> 5, k4 = i4 & 31;
        *(float4*)&w1s[row * 128 + ((k4 ^ ((row >> 2) & 7)) << 2)] = gw1[i4];
    }
    __syncthreads();

    const int jg = tid & 15, ng = tid >> 4, xw = jg & 7;
    const float* ap = &xT[(ng * 4) * SA];
    const float* wp = &w1s[(jg * 4) * 128];
    float acc[4][4] = {};
    #pragma unroll 4
    for (int k4 = 0; k4 < 32; ++k4) {
        const int ko = (k4 ^ xw) << 2;
        float4 w0 = *(const float4*)&wp[0 * 128 + ko];
        float4 w1v = *(const float4*)&wp[1 * 128 + ko];
        float4 w2v = *(const float4*)&wp[2 * 128 + ko];
        float4 w3v = *(const float4*)&wp[3 * 128 + ko];
        #pragma unroll
        for (int i = 0; i < 4; ++i) {
            float4 a = *(const float4*)&ap[i * SA + k4 * 4];
            acc[i][0] = fmaf(a.x, w0.x, fmaf(a.y, w0.y, fmaf(a.z, w0.z, fmaf(a.w, w0.w, acc[i][0]))));
            acc[i][1] = fmaf(a.x, w1v.x, fmaf(a.y, w1v.y, fmaf(a.z, w1v.z, fmaf(a.w, w1v.w, acc[i][1]))));
            acc[i][2] = fmaf(a.x, w2v.x, fmaf(a.y, w2v.y, fmaf(a.z, w2v.z, fmaf(a.w, w2v.w, acc[i][2]))));
            acc[i][3] = fmaf(a.x, w3v.x, fmaf(a.y, w3v.y, fmaf(a.z, w3v.z, fmaf(a.w, w3v.w, acc[i][3]))));
        }
    }
    #pragma unroll
    for (int i = 0; i < 4; ++i) {
        long n = base + ng * 4 + i;
        if (n < n_nodes) {
            float4 v = {acc[i][0], acc[i][1], acc[i][2], acc[i][3]};
            *(float4*)(y + n * 64 + jg * 4) = v;
        }
    }
}

// ===========================================================================
// Gather (64-wide): g[n] = y[n] + sum_{s in adj(n)} y[s].
// float4/lane, 16 lanes per node -> 4 independent node chains per wave,
// edge loop unrolled x2 -> ~8 outstanding row loads per wave.
// ===========================================================================
__global__ __launch_bounds__(256)
void gather64_kernel(const float* __restrict__ y, const int* __restrict__ rowptr,
                     const int* __restrict__ eids, float* __restrict__ g, int n_nodes) {
    int node = blockIdx.x * 16 + (threadIdx.x >> 4);
    if (node >= n_nodes) return;
    int f4 = threadIdx.x & 15;
    const float4* yv = (const float4*)y;
    float4 acc = yv[(long)node * 16 + f4];
    int b = rowptr[node], e = rowptr[node + 1];
    int i = b;
    for (; i + 1 < e; i += 2) {
        int s0 = eids[i], s1 = eids[i + 1];
        float4 r0 = yv[(long)s0 * 16 + f4];
        float4 r1 = yv[(long)s1 * 16 + f4];
        acc.x += r0.x + r1.x;
        acc.y += r0.y + r1.y;
        acc.z += r0.z + r1.z;
        acc.w += r0.w + r1.w;
    }
    if (i < e) {
        int s = eids[i];
        float4 r = yv[(long)s * 16 + f4];
        acc.x += r.x; acc.y += r.y; acc.z += r.z; acc.w += r.w;
    }
    ((float4*)g)[(long)node * 16 + f4] = acc;
}

// ===========================================================================
// Fused mid layer (l=0,1): t = relu(g + b1); h = relu(t@W2s + bias2);
// y_next = h @ W1_next. 64-node tile, two 64x64x64 GEMMs, h kept in LDS
// (reuses the t tile after a barrier).
// ===========================================================================
__global__ __launch_bounds__(256)
void fused_mid_kernel(const float* __restrict__ g, const float* __restrict__ b1,
                      const float* __restrict__ w2sT, const float* __restrict__ bias2,
                      const float* __restrict__ w1nT, float* __restrict__ ynext,
                      int n_nodes) {
    constexpr int SS = 68;
    __shared__ float sT[64 * SS];
    __shared__ float w2s[64 * 64];
    __shared__ float w1n[64 * 64];
    const int tid = threadIdx.x;
    const long base = (long)blockIdx.x * 64;

    // stage t = relu(g + b1)
    const float4* gg = (const float4*)(g + base * 64);
    for (int i4 = tid; i4 < 16 * 64; i4 += 256) {
        int row = i4 >> 4, k4 = i4 & 15;
        float4 v = gg[i4];
        float4 b = *(const float4*)&b1[k4 * 4];
        v.x = fmaxf(v.x + b.x, 0.0f);
        v.y = fmaxf(v.y + b.y, 0.0f);
        v.z = fmaxf(v.z + b.z, 0.0f);
        v.w = fmaxf(v.w + b.w, 0.0f);
        *(float4*)&sT[row * SS + k4 * 4] = v;
    }
    const float4* gw2 = (const float4*)w2sT;
    for (int i4 = tid; i4 < 16 * 64; i4 += 256) {
        int row = i4 >> 4, k4 = i4 & 15;
        *(float4*)&w2s[row * 64 + ((k4 ^ ((row >> 2) & 7)) << 2)] = gw2[i4];
    }
    const float4* gw1n = (const float4*)w1nT;
    for (int i4 = tid; i4 < 16 * 64; i4 += 256) {
        int row = i4 >> 4, k4 = i4 & 15;
        *(float4*)&w1n[row * 64 + ((k4 ^ ((row >> 2) & 7)) << 2)] = gw1n[i4];
    }
    __syncthreads();

    const int jg = tid & 15, ng = tid >> 4, xw = jg & 7;

    // GEMM A: h = relu(t @ w2s + bias2)
    float h[4][4];
    {
        const float* ap = &sT[(ng * 4) * SS];
        const float* wp = &w2s[(jg * 4) * 64];
        float acc[4][4] = {};
        #pragma unroll 4
        for (int k4 = 0; k4 < 16; ++k4) {
            const int ko = (k4 ^ xw) << 2;
            float4 w0 = *(const float4*)&wp[0 * 64 + ko];
            float4 w1v = *(const float4*)&wp[1 * 64 + ko];
            float4 w2v = *(const float4*)&wp[2 * 64 + ko];
            float4 w3v = *(const float4*)&wp[3 * 64 + ko];
            #pragma unroll
            for (int i = 0; i < 4; ++i) {
                float4 a = *(const float4*)&ap[i * SS + k4 * 4];
                acc[i][0] = fmaf(a.x, w0.x, fmaf(a.y, w0.y, fmaf(a.z, w0.z, fmaf(a.w, w0.w, acc[i][0]))));
                acc[i][1] = fmaf(a.x, w1v.x, fmaf(a.y, w1v.y, fmaf(a.z, w1v.z, fmaf(a.w, w1v.w, acc[i][1]))));
                acc[i][2] = fmaf(a.x, w2v.x, fmaf(a.y, w2v.y, fmaf(a.z, w2v.z, fmaf(a.w, w2v.w, acc[i][2]))));
                acc[i][3] = fmaf(a.x, w3v.x, fmaf(a.y, w3v.y, fmaf(a.z, w3v.z, fmaf(a.w, w3v.w, acc[i][3]))));
            }
        }
        float4 bv = *(const float4*)&bias2[jg * 4];
        #pragma unroll
        for (int i = 0; i < 4; ++i) {
            h[i][0] = fmaxf(acc[i][0] + bv.x, 0.0f);
            h[i][1] = fmaxf(acc[i][1] + bv.y, 0.0f);
            h[i][2] = fmaxf(acc[i][2] + bv.z, 0.0f);
            h[i][3] = fmaxf(acc[i][3] + bv.w, 0.0f);
        }
    }
    __syncthreads();  // everyone done reading t
    #pragma unroll
    for (int i = 0; i < 4; ++i) {
        float4 hv = {h[i][0], h[i][1], h[i][2], h[i][3]};
        *(float4*)&sT[(ng * 4 + i) * SS + jg * 4] = hv;
    }
    __syncthreads();

    // GEMM B: y_next = h @ w1n
    {
        const float* ap = &sT[(ng * 4) * SS];
        const float* wp = &w1n[(jg * 4) * 64];
        float acc[4][4] = {};
        #pragma unroll 4
        for (int k4 = 0; k4 < 16; ++k4) {
            const int ko = (k4 ^ xw) << 2;
            float4 w0 = *(const float4*)&wp[0 * 64 + ko];
            float4 w1v = *(const float4*)&wp[1 * 64 + ko];
            float4 w2v = *(const float4*)&wp[2 * 64 + ko];
            float4 w3v = *(const float4*)&wp[3 * 64 + ko];
            #pragma unroll
            for (int i = 0; i < 4; ++i) {
                float4 a = *(const float4*)&ap[i * SS + k4 * 4];
                acc[i][0] = fmaf(a.x, w0.x, fmaf(a.y, w0.y, fmaf(a.z, w0.z, fmaf(a.w, w0.w, acc[i][0]))));
                acc[i][1] = fmaf(a.x, w1v.x, fmaf(a.y, w1v.y, fmaf(a.z, w1v.z, fmaf(a.w, w1v.w, acc[i][1]))));
                acc[i][2] = fmaf(a.x, w2v.x, fmaf(a.y, w2v.y, fmaf(a.z, w2v.z, fmaf(a.w, w2v.w, acc[i][2]))));
                acc[i][3] = fmaf(a.x, w3v.x, fmaf(a.y, w3v.y, fmaf(a.z, w3v.z, fmaf(a.w, w3v.w, acc[i][3]))));
            }
        }
        #pragma unroll
        for (int i = 0; i < 4; ++i) {
            long n = base + ng * 4 + i;
            if (n < n_nodes) {
                float4 v = {acc[i][0], acc[i][1], acc[i][2], acc[i][3]};
                *(float4*)(ynext + n * 64 + jg * 4) = v;
            }
        }
    }
}

// ===========================================================================
// Fused final layer (l=2): t = relu(g + b1); out = relu(t@W2s + bias2), 96-wide.
// ===========================================================================
__global__ __launch_bounds__(256)
void fused_final_kernel(const float* __restrict__ g, const float* __restrict__ b1,
                        const float* __restrict__ w2sT, const float* __restrict__ bias2,
                        float* __restrict__ out, int n_nodes) {
    constexpr int SS = 68;
    constexpr int CPT = 6;
    __shared__ float sT[64 * SS];
    __shared__ float w2s[96 * 64];
    const int tid = threadIdx.x;
    const long base = (long)blockIdx.x * 64;

    const float4* gg = (const float4*)(g + base * 64);
    for (int i4 = tid; i4 < 16 * 64; i4 += 256) {
        int row = i4 >> 4, k4 = i4 & 15;
        float4 v = gg[i4];
        float4 b = *(const float4*)&b1[k4 * 4];
        v.x = fmaxf(v.x + b.x, 0.0f);
        v.y = fmaxf(v.y + b.y, 0.0f);
        v.z = fmaxf(v.z + b.z, 0.0f);
        v.w = fmaxf(v.w + b.w, 0.0f);
        *(float4*)&sT[row * SS + k4 * 4] = v;
    }
    const float4* gw2 = (const float4*)w2sT;
    for (int i4 = tid; i4 < 96 * 16; i4 += 256) {
        int row = i4 >> 4, k4 = i4 & 15;
        *(float4*)&w2s[row * 64 + ((k4 ^ ((row / CPT) & 7)) << 2)] = gw2[i4];
    }
    __syncthreads();

    const int cg = tid & 15, ng = tid >> 4, xw = cg & 7;
    const float* hp = &sT[(ng * 4) * SS];
    const float* wp = &w2s[(cg * CPT) * 64];
    float acc[4][CPT] = {};
    #pragma unroll 4
    for (int k4 = 0; k4 < 16; ++k4) {
        const int ko = (k4 ^ xw) << 2;
        float4 wv[CPT];
        #pragma unroll
        for (int c = 0; c < CPT; ++c) wv[c] = *(const float4*)&wp[c * 64 + ko];
        #pragma unroll
        for (int i = 0; i < 4; ++i) {
            float4 h = *(const float4*)&hp[i * SS + k4 * 4];
            #pragma unroll
            for (int c = 0; c < CPT; ++c)
                acc[i][c] = fmaf(h.x, wv[c].x, fmaf(h.y, wv[c].y, fmaf(h.z, wv[c].z, fmaf(h.w, wv[c].w, acc[i][c]))));
        }
    }
    float bv[CPT];
    #pragma unroll
    for (int c = 0; c < CPT; ++c) bv[c] = bias2[cg * CPT + c];
    #pragma unroll
    for (int i = 0; i < 4; ++i) {
        long n = base + ng * 4 + i;
        if (n < n_nodes) {
            float* op = out + n * 96 + cg * CPT;
            #pragma unroll
            for (int c = 0; c < CPT; ++c) op[c] = fmaxf(acc[i][c] + bv[c], 0.0f);
        }
    }
}

// ===========================================================================
// Mean-pool + finalize
// ===========================================================================
#define POOL_CHUNK 256
__global__ void pool_kernel(const float* __restrict__ h,
                            const int* __restrict__ batch,
                            float* __restrict__ sums,
                            float* __restrict__ counts,
                            int n_nodes) {
    __shared__ float acc[N_GRAPHS * 96];
    __shared__ float cnt[N_GRAPHS];
    for (int i = threadIdx.x; i < N_GRAPHS * 96; i += blockDim.x) acc[i] = 0.0f;
    for (int i = threadIdx.x; i < N_GRAPHS; i += blockDim.x) cnt[i] = 0.0f;
    __syncthreads();
    int f = threadIdx.x;
    int start = blockIdx.x * POOL_CHUNK;
    int end = start + POOL_CHUNK;
    if (end > n_nodes) end = n_nodes;
    if (f < 96) {
        for (int n = start; n < end; ++n) {
            int g = batch[n];
            acc[g * 96 + f] += h[(long)n * 96 + f];
            if (f == 0) cnt[g] += 1.0f;
        }
    }
    __syncthreads();
    for (int i = threadIdx.x; i < N_GRAPHS * 96; i += blockDim.x)
        if (acc[i] != 0.0f) atomicAdd(&sums[i], acc[i]);
    for (int i = threadIdx.x; i < N_GRAPHS; i += blockDim.x)
        if (cnt[i] != 0.0f) atomicAdd(&counts[i], cnt[i]);
}

__global__ void finalize_kernel(const float* __restrict__ sums,
                                const float* __restrict__ counts,
                                float* __restrict__ out) {
    int i = blockIdx.x * blockDim.x + threadIdx.x;
    if (i >= N_GRAPHS * 96) return;
    int g = i / 96;
    out[i] = sums[i] / fmaxf(counts[g], 1.0f);
}

// ---------------------------------------------------------------------------
static inline int cdiv_l(long a, int b) { return (int)((a + b - 1) / b); }

extern "C" void kernel_launch(void* const* d_in, const int* in_sizes, int n_in,
                              void* d_out, int out_size, void* d_ws, size_t ws_size,
                              hipStream_t stream) {
    const float* x     = (const float*)d_in[0];
    const int*   ei    = (const int*)d_in[1];
    const int*   src   = ei;
    const int*   dst   = ei + N_EDGES;
    const int*   batch = (const int*)d_in[2];

    const float* P[3][8];
    int p = 3;
    for (int l = 0; l < 3; ++l)
        for (int q = 0; q < 8; ++q)
            P[l][q] = (const float*)d_in[p++];

    // Workspace (NP = +64 row padding so tile staging never leaves the ws)
    const long NP = N_NODES + 64;
    float* ws   = (float*)d_ws;
    float* yT   = ws;               // NP*64  (pre-transformed features)
    float* gB   = yT + NP * 64;     // NP*64  (gathered)
    float* h2   = gB + NP * 64;     // NP*96  (final node features)
    float* q    = h2 + NP * 96;
    float* w1T[3], *w2sT[3], *bias2[3];
    for (int l = 0; l < 3; ++l) {
        w1T[l] = q;   q += 64 * 128;
        w2sT[l] = q;  q += 96 * 64;
        bias2[l] = q; q += 96;
    }
    float* sums   = q;
    float* counts = sums + N_GRAPHS * 96;
    int* deg      = (int*)(counts + N_GRAPHS);
    int* cursor   = deg + N_NODES;
    int* partials = cursor + N_NODES;
    int* rowptr   = partials + 128;
    int* eids     = rowptr + (N_NODES + 1);

    const int B = 256;
    const int DIN[3]  = {128, 64, 64};
    const int DOUT[3] = {64, 64, 96};

    // ---- prep (independent of CSR) ----
    for (int l = 0; l < 3; ++l) {
        int tot = 64 * DIN[l] + 64 * DOUT[l] + DOUT[l];
        prep_kernel<<<cdiv_l(tot, B), B, 0, stream>>>(
            P[l][0], P[l][2], P[l][3], P[l][4], P[l][5], P[l][6], P[l][7],
            w1T[l], w2sT[l], bias2[l], DIN[l], DOUT[l]);
    }

    // ---- CSR build ----
    hipMemsetAsync(deg, 0, (size_t)(2 * N_NODES + 128) * sizeof(int), stream);
    deg_hist_kernel<<<cdiv_l(N_EDGES, B), B, 0, stream>>>(dst, deg, N_EDGES);
    int nblk = cdiv_l(N_NODES, 1024);
    scan1_kernel<<<nblk, 1024, 0, stream>>>(deg, rowptr, partials, N_NODES);
    scan2_kernel<<<1, 128, 0, stream>>>(partials, nblk);
    scan3_kernel<<<cdiv_l(N_NODES + 1, B), B, 0, stream>>>(rowptr, partials, N_NODES, N_EDGES);
    csr_fill_kernel<<<cdiv_l(N_EDGES, B), B, 0, stream>>>(src, dst, rowptr, cursor, eids, N_EDGES);

    const int ntiles = cdiv_l(N_NODES, 64);
    const int ngather = cdiv_l(N_NODES, 16);

    // ---- layer 0 ----
    pre_gemm_kernel<<<ntiles, 256, 0, stream>>>(x, w1T[0], yT, N_NODES);
    gather64_kernel<<<ngather, 256, 0, stream>>>(yT, rowptr, eids, gB, N_NODES);
    fused_mid_kernel<<<ntiles, 256, 0, stream>>>(
        gB, P[0][1], w2sT[0], bias2[0], w1T[1], yT, N_NODES);
    // ---- layer 1 ----
    gather64_kernel<<<ngather, 256, 0, stream>>>(yT, rowptr, eids, gB, N_NODES);
    fused_mid_kernel<<<ntiles, 256, 0, stream>>>(
        gB, P[1][1], w2sT[1], bias2[1], w1T[2], yT, N_NODES);
    // ---- layer 2 ----
    gather64_kernel<<<ngather, 256, 0, stream>>>(yT, rowptr, eids, gB, N_NODES);
    fused_final_kernel<<<ntiles, 256, 0, stream>>>(
        gB, P[2][1], w2sT[2], bias2[2], h2, N_NODES);

    // ---- global mean pool ----
    hipMemsetAsync(sums, 0, (size_t)(N_GRAPHS * 96 + N_GRAPHS) * sizeof(float), stream);
    pool_kernel<<<cdiv_l(N_NODES, POOL_CHUNK), 128, 0, stream>>>(
        h2, batch, sums, counts, N_NODES);
    finalize_kernel<<<cdiv_l(N_GRAPHS * 96, B), B, 0, stream>>>(
        sums, counts, (float*)d_out);
}

// Round 5
// 432.151 us; speedup vs baseline: 3.3741x; 1.1959x over previous
//
#include <hip/hip_runtime.h>

#define N_NODES 100000
#define N_GRAPHS 64
#define N_EDGES 600000
#define BN_EPS 1e-5f

// ===========================================================================
// CSR build: deg histogram -> scan -> cursor fill.
// ===========================================================================
__global__ void deg_hist_kernel(const int* __restrict__ dst,
                                int* __restrict__ deg, int n_edges) {
    int e = blockIdx.x * blockDim.x + threadIdx.x;
    if (e < n_edges) atomicAdd(&deg[dst[e]], 1);
}

__global__ void scan1_kernel(const int* __restrict__ deg, int* __restrict__ excl,
                             int* __restrict__ partials, int n) {
    __shared__ int s[1024];
    int i = blockIdx.x * 1024 + threadIdx.x;
    int v = (i < n) ? deg[i] : 0;
    s[threadIdx.x] = v;
    __syncthreads();
    for (int off = 1; off < 1024; off <<= 1) {
        int t = (threadIdx.x >= (unsigned)off) ? s[threadIdx.x - off] : 0;
        __syncthreads();
        s[threadIdx.x] += t;
        __syncthreads();
    }
    if (i < n) excl[i] = s[threadIdx.x] - v;
    if (threadIdx.x == 1023) partials[blockIdx.x] = s[1023];
}

__global__ void scan2_kernel(int* partials, int nb) {
    __shared__ int s[128];
    int t = threadIdx.x;
    int v = (t < nb) ? partials[t] : 0;
    s[t] = v;
    __syncthreads();
    for (int off = 1; off < 128; off <<= 1) {
        int u = (t >= off) ? s[t - off] : 0;
        __syncthreads();
        s[t] += u;
        __syncthreads();
    }
    if (t < nb) partials[t] = s[t] - v;
}

__global__ void scan3_kernel(int* __restrict__ rowptr, const int* __restrict__ partials,
                             int n, int total) {
    int i = blockIdx.x * blockDim.x + threadIdx.x;
    if (i < n) rowptr[i] += partials[i >> 10];
    else if (i == n) rowptr[n] = total;
}

__global__ void csr_fill_kernel(const int* __restrict__ src, const int* __restrict__ dst,
                                const int* __restrict__ rowptr, int* __restrict__ cursor,
                                int* __restrict__ eids, int n_edges) {
    int e = blockIdx.x * blockDim.x + threadIdx.x;
    if (e >= n_edges) return;
    int t = dst[e];
    int pos = rowptr[t] + atomicAdd(&cursor[t], 1);
    eids[pos] = src[e];
}

// ===========================================================================
// Graph boundaries from sorted batch: gstart[g] = first node of graph g,
// gstart[N_GRAPHS] = n_nodes. Handles empty graphs.
// ===========================================================================
__global__ void graph_bounds_kernel(const int* __restrict__ batch,
                                    int* __restrict__ gstart, int n_nodes) {
    int n = blockIdx.x * blockDim.x + threadIdx.x;
    if (n >= n_nodes) return;
    if (n == 0) {
        for (int g = 0; g <= batch[0]; ++g) gstart[g] = 0;
    } else {
        int b0 = batch[n - 1], b1 = batch[n];
        for (int g = b0 + 1; g <= b1; ++g) gstart[g] = n;
    }
    if (n == n_nodes - 1) {
        for (int g = batch[n] + 1; g <= N_GRAPHS; ++g) gstart[g] = n_nodes;
    }
}

// ===========================================================================
// Prep per layer: w1T[j][k] = w1[k][j]; w2sT[c][j] = w2[j][c]*s[c];
// bias2[c] = (b2[c]-m[c])*s[c]+bb[c].
// ===========================================================================
__global__ void prep_kernel(const float* __restrict__ w1, const float* __restrict__ w2,
                            const float* __restrict__ b2, const float* __restrict__ g,
                            const float* __restrict__ bb, const float* __restrict__ m,
                            const float* __restrict__ v,
                            float* __restrict__ w1T, float* __restrict__ w2sT,
                            float* __restrict__ bias2, int DIN, int DOUT) {
    int i = blockIdx.x * blockDim.x + threadIdx.x;
    if (i < 64 * DIN) {
        int j = i / DIN, k = i % DIN;
        w1T[i] = w1[k * 64 + j];
    }
    int i2 = i - 64 * DIN;
    if (i2 >= 0 && i2 < DOUT * 64) {
        int c = i2 / 64, j = i2 % 64;
        float s = g[c] * rsqrtf(v[c] + BN_EPS);
        w2sT[i2] = w2[j * DOUT + c] * s;
    }
    int i3 = i2 - DOUT * 64;
    if (i3 >= 0 && i3 < DOUT) {
        float s = g[i3] * rsqrtf(v[i3] + BN_EPS);
        bias2[i3] = (b2[i3] - m[i3]) * s + bb[i3];
    }
}

// ===========================================================================
// pre-GEMM: y = x @ W1_0  (100k x 128 -> 100k x 64). 64-node tile per block.
// ===========================================================================
__global__ __launch_bounds__(256)
void pre_gemm_kernel(const float* __restrict__ x, const float* __restrict__ w1T,
                     float* __restrict__ y, int n_nodes) {
    constexpr int SA = 132;
    __shared__ float xT[64 * SA];
    __shared__ float w1s[64 * 128];
    const int tid = threadIdx.x;
    const long base = (long)blockIdx.x * 64;

    for (int i4 = tid; i4 < 16 * 128; i4 += 256) {
        int row = i4 >> 5, k4 = i4 & 31;
        long r = base + row;
        if (r >= n_nodes) r = n_nodes - 1;  // clamp: x is an input, no padding
        *(float4*)&xT[row * SA + k4 * 4] = ((const float4*)x)[r * 32 + k4];
    }
    const float4* gw1 = (const float4*)w1T;
    for (int i4 = tid; i4 < 16 * 128; i4 += 256) {
        int row = i4 >> 5, k4 = i4 & 31;
        *(float4*)&w1s[row * 128 + ((k4 ^ ((row >> 2) & 7)) << 2)] = gw1[i4];
    }
    __syncthreads();

    const int jg = tid & 15, ng = tid >> 4, xw = jg & 7;
    const float* ap = &xT[(ng * 4) * SA];
    const float* wp = &w1s[(jg * 4) * 128];
    float acc[4][4] = {};
    #pragma unroll 4
    for (int k4 = 0; k4 < 32; ++k4) {
        const int ko = (k4 ^ xw) << 2;
        float4 w0 = *(const float4*)&wp[0 * 128 + ko];
        float4 w1v = *(const float4*)&wp[1 * 128 + ko];
        float4 w2v = *(const float4*)&wp[2 * 128 + ko];
        float4 w3v = *(const float4*)&wp[3 * 128 + ko];
        #pragma unroll
        for (int i = 0; i < 4; ++i) {
            float4 a = *(const float4*)&ap[i * SA + k4 * 4];
            acc[i][0] = fmaf(a.x, w0.x, fmaf(a.y, w0.y, fmaf(a.z, w0.z, fmaf(a.w, w0.w, acc[i][0]))));
            acc[i][1] = fmaf(a.x, w1v.x, fmaf(a.y, w1v.y, fmaf(a.z, w1v.z, fmaf(a.w, w1v.w, acc[i][1]))));
            acc[i][2] = fmaf(a.x, w2v.x, fmaf(a.y, w2v.y, fmaf(a.z, w2v.z, fmaf(a.w, w2v.w, acc[i][2]))));
            acc[i][3] = fmaf(a.x, w3v.x, fmaf(a.y, w3v.y, fmaf(a.z, w3v.z, fmaf(a.w, w3v.w, acc[i][3]))));
        }
    }
    #pragma unroll
    for (int i = 0; i < 4; ++i) {
        long n = base + ng * 4 + i;
        if (n < n_nodes) {
            float4 v = {acc[i][0], acc[i][1], acc[i][2], acc[i][3]};
            *(float4*)(y + n * 64 + jg * 4) = v;
        }
    }
}

// ===========================================================================
// Gather (64-wide): g[n] = y[n] + sum_{s in adj(n)} y[s].
// float4/lane, 16 lanes/node -> 4 node chains/wave; unroll x4 -> up to
// 16 outstanding row loads per wave.
// ===========================================================================
__global__ __launch_bounds__(256)
void gather64_kernel(const float* __restrict__ y, const int* __restrict__ rowptr,
                     const int* __restrict__ eids, float* __restrict__ g, int n_nodes) {
    int node = blockIdx.x * 16 + (threadIdx.x >> 4);
    if (node >= n_nodes) return;
    int f4 = threadIdx.x & 15;
    const float4* yv = (const float4*)y;
    float4 acc = yv[(long)node * 16 + f4];
    int b = rowptr[node], e = rowptr[node + 1];
    int i = b;
    for (; i + 3 < e; i += 4) {
        int s0 = eids[i], s1 = eids[i + 1], s2 = eids[i + 2], s3 = eids[i + 3];
        float4 r0 = yv[(long)s0 * 16 + f4];
        float4 r1 = yv[(long)s1 * 16 + f4];
        float4 r2 = yv[(long)s2 * 16 + f4];
        float4 r3 = yv[(long)s3 * 16 + f4];
        acc.x += (r0.x + r1.x) + (r2.x + r3.x);
        acc.y += (r0.y + r1.y) + (r2.y + r3.y);
        acc.z += (r0.z + r1.z) + (r2.z + r3.z);
        acc.w += (r0.w + r1.w) + (r2.w + r3.w);
    }
    for (; i < e; ++i) {
        int s = eids[i];
        float4 r = yv[(long)s * 16 + f4];
        acc.x += r.x; acc.y += r.y; acc.z += r.z; acc.w += r.w;
    }
    ((float4*)g)[(long)node * 16 + f4] = acc;
}

// ===========================================================================
// Fused mid layer (l=0,1): t = relu(g + b1); h = relu(t@W2s + bias2);
// y_next = h @ W1_next.
// ===========================================================================
__global__ __launch_bounds__(256)
void fused_mid_kernel(const float* __restrict__ g, const float* __restrict__ b1,
                      const float* __restrict__ w2sT, const float* __restrict__ bias2,
                      const float* __restrict__ w1nT, float* __restrict__ ynext,
                      int n_nodes) {
    constexpr int SS = 68;
    __shared__ float sT[64 * SS];
    __shared__ float w2s[64 * 64];
    __shared__ float w1n[64 * 64];
    const int tid = threadIdx.x;
    const long base = (long)blockIdx.x * 64;

    const float4* gg = (const float4*)(g + base * 64);
    for (int i4 = tid; i4 < 16 * 64; i4 += 256) {
        int row = i4 >> 4, k4 = i4 & 15;
        float4 v = gg[i4];
        float4 b = *(const float4*)&b1[k4 * 4];
        v.x = fmaxf(v.x + b.x, 0.0f);
        v.y = fmaxf(v.y + b.y, 0.0f);
        v.z = fmaxf(v.z + b.z, 0.0f);
        v.w = fmaxf(v.w + b.w, 0.0f);
        *(float4*)&sT[row * SS + k4 * 4] = v;
    }
    const float4* gw2 = (const float4*)w2sT;
    for (int i4 = tid; i4 < 16 * 64; i4 += 256) {
        int row = i4 >> 4, k4 = i4 & 15;
        *(float4*)&w2s[row * 64 + ((k4 ^ ((row >> 2) & 7)) << 2)] = gw2[i4];
    }
    const float4* gw1n = (const float4*)w1nT;
    for (int i4 = tid; i4 < 16 * 64; i4 += 256) {
        int row = i4 >> 4, k4 = i4 & 15;
        *(float4*)&w1n[row * 64 + ((k4 ^ ((row >> 2) & 7)) << 2)] = gw1n[i4];
    }
    __syncthreads();

    const int jg = tid & 15, ng = tid >> 4, xw = jg & 7;

    float h[4][4];
    {
        const float* ap = &sT[(ng * 4) * SS];
        const float* wp = &w2s[(jg * 4) * 64];
        float acc[4][4] = {};
        #pragma unroll 4
        for (int k4 = 0; k4 < 16; ++k4) {
            const int ko = (k4 ^ xw) << 2;
            float4 w0 = *(const float4*)&wp[0 * 64 + ko];
            float4 w1v = *(const float4*)&wp[1 * 64 + ko];
            float4 w2v = *(const float4*)&wp[2 * 64 + ko];
            float4 w3v = *(const float4*)&wp[3 * 64 + ko];
            #pragma unroll
            for (int i = 0; i < 4; ++i) {
                float4 a = *(const float4*)&ap[i * SS + k4 * 4];
                acc[i][0] = fmaf(a.x, w0.x, fmaf(a.y, w0.y, fmaf(a.z, w0.z, fmaf(a.w, w0.w, acc[i][0]))));
                acc[i][1] = fmaf(a.x, w1v.x, fmaf(a.y, w1v.y, fmaf(a.z, w1v.z, fmaf(a.w, w1v.w, acc[i][1]))));
                acc[i][2] = fmaf(a.x, w2v.x, fmaf(a.y, w2v.y, fmaf(a.z, w2v.z, fmaf(a.w, w2v.w, acc[i][2]))));
                acc[i][3] = fmaf(a.x, w3v.x, fmaf(a.y, w3v.y, fmaf(a.z, w3v.z, fmaf(a.w, w3v.w, acc[i][3]))));
            }
        }
        float4 bv = *(const float4*)&bias2[jg * 4];
        #pragma unroll
        for (int i = 0; i < 4; ++i) {
            h[i][0] = fmaxf(acc[i][0] + bv.x, 0.0f);
            h[i][1] = fmaxf(acc[i][1] + bv.y, 0.0f);
            h[i][2] = fmaxf(acc[i][2] + bv.z, 0.0f);
            h[i][3] = fmaxf(acc[i][3] + bv.w, 0.0f);
        }
    }
    __syncthreads();
    #pragma unroll
    for (int i = 0; i < 4; ++i) {
        float4 hv = {h[i][0], h[i][1], h[i][2], h[i][3]};
        *(float4*)&sT[(ng * 4 + i) * SS + jg * 4] = hv;
    }
    __syncthreads();

    {
        const float* ap = &sT[(ng * 4) * SS];
        const float* wp = &w1n[(jg * 4) * 64];
        float acc[4][4] = {};
        #pragma unroll 4
        for (int k4 = 0; k4 < 16; ++k4) {
            const int ko = (k4 ^ xw) << 2;
            float4 w0 = *(const float4*)&wp[0 * 64 + ko];
            float4 w1v = *(const float4*)&wp[1 * 64 + ko];
            float4 w2v = *(const float4*)&wp[2 * 64 + ko];
            float4 w3v = *(const float4*)&wp[3 * 64 + ko];
            #pragma unroll
            for (int i = 0; i < 4; ++i) {
                float4 a = *(const float4*)&ap[i * SS + k4 * 4];
                acc[i][0] = fmaf(a.x, w0.x, fmaf(a.y, w0.y, fmaf(a.z, w0.z, fmaf(a.w, w0.w, acc[i][0]))));
                acc[i][1] = fmaf(a.x, w1v.x, fmaf(a.y, w1v.y, fmaf(a.z, w1v.z, fmaf(a.w, w1v.w, acc[i][1]))));
                acc[i][2] = fmaf(a.x, w2v.x, fmaf(a.y, w2v.y, fmaf(a.z, w2v.z, fmaf(a.w, w2v.w, acc[i][2]))));
                acc[i][3] = fmaf(a.x, w3v.x, fmaf(a.y, w3v.y, fmaf(a.z, w3v.z, fmaf(a.w, w3v.w, acc[i][3]))));
            }
        }
        #pragma unroll
        for (int i = 0; i < 4; ++i) {
            long n = base + ng * 4 + i;
            if (n < n_nodes) {
                float4 v = {acc[i][0], acc[i][1], acc[i][2], acc[i][3]};
                *(float4*)(ynext + n * 64 + jg * 4) = v;
            }
        }
    }
}

// ===========================================================================
// Fused final layer (l=2): t = relu(g + b1); out = relu(t@W2s + bias2), 96-wide.
// ===========================================================================
__global__ __launch_bounds__(256)
void fused_final_kernel(const float* __restrict__ g, const float* __restrict__ b1,
                        const float* __restrict__ w2sT, const float* __restrict__ bias2,
                        float* __restrict__ out, int n_nodes) {
    constexpr int SS = 68;
    constexpr int CPT = 6;
    __shared__ float sT[64 * SS];
    __shared__ float w2s[96 * 64];
    const int tid = threadIdx.x;
    const long base = (long)blockIdx.x * 64;

    const float4* gg = (const float4*)(g + base * 64);
    for (int i4 = tid; i4 < 16 * 64; i4 += 256) {
        int row = i4 >> 4, k4 = i4 & 15;
        float4 v = gg[i4];
        float4 b = *(const float4*)&b1[k4 * 4];
        v.x = fmaxf(v.x + b.x, 0.0f);
        v.y = fmaxf(v.y + b.y, 0.0f);
        v.z = fmaxf(v.z + b.z, 0.0f);
        v.w = fmaxf(v.w + b.w, 0.0f);
        *(float4*)&sT[row * SS + k4 * 4] = v;
    }
    const float4* gw2 = (const float4*)w2sT;
    for (int i4 = tid; i4 < 96 * 16; i4 += 256) {
        int row = i4 >> 4, k4 = i4 & 15;
        *(float4*)&w2s[row * 64 + ((k4 ^ ((row / CPT) & 7)) << 2)] = gw2[i4];
    }
    __syncthreads();

    const int cg = tid & 15, ng = tid >> 4, xw = cg & 7;
    const float* hp = &sT[(ng * 4) * SS];
    const float* wp = &w2s[(cg * CPT) * 64];
    float acc[4][CPT] = {};
    #pragma unroll 4
    for (int k4 = 0; k4 < 16; ++k4) {
        const int ko = (k4 ^ xw) << 2;
        float4 wv[CPT];
        #pragma unroll
        for (int c = 0; c < CPT; ++c) wv[c] = *(const float4*)&wp[c * 64 + ko];
        #pragma unroll
        for (int i = 0; i < 4; ++i) {
            float4 h = *(const float4*)&hp[i * SS + k4 * 4];
            #pragma unroll
            for (int c = 0; c < CPT; ++c)
                acc[i][c] = fmaf(h.x, wv[c].x, fmaf(h.y, wv[c].y, fmaf(h.z, wv[c].z, fmaf(h.w, wv[c].w, acc[i][c]))));
        }
    }
    float bv[CPT];
    #pragma unroll
    for (int c = 0; c < CPT; ++c) bv[c] = bias2[cg * CPT + c];
    #pragma unroll
    for (int i = 0; i < 4; ++i) {
        long n = base + ng * 4 + i;
        if (n < n_nodes) {
            float* op = out + n * 96 + cg * CPT;
            #pragma unroll
            for (int c = 0; c < CPT; ++c) op[c] = fmaxf(acc[i][c] + bv[c], 0.0f);
        }
    }
}

// ===========================================================================
// Mean-pool over sorted batch via graph boundaries. Grid = 64 graphs x 16
// segments; 192 threads = 8 node-chains x 24 float4-lanes. Register
// accumulate, LDS tree-reduce chains, 96 atomics per block.
// ===========================================================================
#define POOL_SPLIT 16
__global__ __launch_bounds__(192)
void pool_seg_kernel(const float* __restrict__ h, const int* __restrict__ gstart,
                     float* __restrict__ sums) {
    int g = blockIdx.x >> 4;
    int s = blockIdx.x & 15;
    int lo = gstart[g], hi = gstart[g + 1];
    int len = hi - lo;
    int seg = (len + POOL_SPLIT - 1) / POOL_SPLIT;
    int a = lo + s * seg;
    int b = a + seg; if (b > hi) b = hi;

    int f4 = threadIdx.x % 24;
    int chain = threadIdx.x / 24;  // 0..7
    const float4* hv = (const float4*)h;
    float4 acc = {0.0f, 0.0f, 0.0f, 0.0f};
    for (int n = a + chain; n < b; n += 8) {
        float4 v = hv[(long)n * 24 + f4];
        acc.x += v.x; acc.y += v.y; acc.z += v.z; acc.w += v.w;
    }
    __shared__ float4 red[8][24];
    red[chain][f4] = acc;
    __syncthreads();
    if (threadIdx.x < 24) {
        float4 t = red[0][threadIdx.x];
        #pragma unroll
        for (int c = 1; c < 8; ++c) {
            float4 r = red[c][threadIdx.x];
            t.x += r.x; t.y += r.y; t.z += r.z; t.w += r.w;
        }
        float* sp = &sums[g * 96 + threadIdx.x * 4];
        atomicAdd(sp + 0, t.x);
        atomicAdd(sp + 1, t.y);
        atomicAdd(sp + 2, t.z);
        atomicAdd(sp + 3, t.w);
    }
}

__global__ void finalize_kernel(const float* __restrict__ sums,
                                const int* __restrict__ gstart,
                                float* __restrict__ out) {
    int i = blockIdx.x * blockDim.x + threadIdx.x;
    if (i >= N_GRAPHS * 96) return;
    int g = i / 96;
    float cnt = (float)(gstart[g + 1] - gstart[g]);
    out[i] = sums[i] / fmaxf(cnt, 1.0f);
}

// ---------------------------------------------------------------------------
static inline int cdiv_l(long a, int b) { return (int)((a + b - 1) / b); }

extern "C" void kernel_launch(void* const* d_in, const int* in_sizes, int n_in,
                              void* d_out, int out_size, void* d_ws, size_t ws_size,
                              hipStream_t stream) {
    const float* x     = (const float*)d_in[0];
    const int*   ei    = (const int*)d_in[1];
    const int*   src   = ei;
    const int*   dst   = ei + N_EDGES;
    const int*   batch = (const int*)d_in[2];

    const float* P[3][8];
    int p = 3;
    for (int l = 0; l < 3; ++l)
        for (int q = 0; q < 8; ++q)
            P[l][q] = (const float*)d_in[p++];

    const long NP = N_NODES + 64;
    float* ws   = (float*)d_ws;
    float* yT   = ws;               // NP*64
    float* gB   = yT + NP * 64;     // NP*64
    float* h2   = gB + NP * 64;     // NP*96
    float* q    = h2 + NP * 96;
    float* w1T[3], *w2sT[3], *bias2[3];
    for (int l = 0; l < 3; ++l) {
        w1T[l] = q;   q += 64 * 128;
        w2sT[l] = q;  q += 96 * 64;
        bias2[l] = q; q += 96;
    }
    float* sums   = q;
    int* gstart   = (int*)(sums + N_GRAPHS * 96);   // 65
    int* deg      = gstart + 72;
    int* cursor   = deg + N_NODES;
    int* partials = cursor + N_NODES;
    int* rowptr   = partials + 128;
    int* eids     = rowptr + (N_NODES + 1);

    const int B = 256;
    const int DIN[3]  = {128, 64, 64};
    const int DOUT[3] = {64, 64, 96};

    // ---- prep (independent of CSR) ----
    for (int l = 0; l < 3; ++l) {
        int tot = 64 * DIN[l] + 64 * DOUT[l] + DOUT[l];
        prep_kernel<<<cdiv_l(tot, B), B, 0, stream>>>(
            P[l][0], P[l][2], P[l][3], P[l][4], P[l][5], P[l][6], P[l][7],
            w1T[l], w2sT[l], bias2[l], DIN[l], DOUT[l]);
    }

    // ---- CSR build + graph bounds ----
    hipMemsetAsync(deg, 0, (size_t)(2 * N_NODES + 128) * sizeof(int), stream);
    deg_hist_kernel<<<cdiv_l(N_EDGES, B), B, 0, stream>>>(dst, deg, N_EDGES);
    int nblk = cdiv_l(N_NODES, 1024);
    scan1_kernel<<<nblk, 1024, 0, stream>>>(deg, rowptr, partials, N_NODES);
    scan2_kernel<<<1, 128, 0, stream>>>(partials, nblk);
    scan3_kernel<<<cdiv_l(N_NODES + 1, B), B, 0, stream>>>(rowptr, partials, N_NODES, N_EDGES);
    csr_fill_kernel<<<cdiv_l(N_EDGES, B), B, 0, stream>>>(src, dst, rowptr, cursor, eids, N_EDGES);
    graph_bounds_kernel<<<cdiv_l(N_NODES, B), B, 0, stream>>>(batch, gstart, N_NODES);

    const int ntiles = cdiv_l(N_NODES, 64);
    const int ngather = cdiv_l(N_NODES, 16);

    // ---- layer 0 ----
    pre_gemm_kernel<<<ntiles, 256, 0, stream>>>(x, w1T[0], yT, N_NODES);
    gather64_kernel<<<ngather, 256, 0, stream>>>(yT, rowptr, eids, gB, N_NODES);
    fused_mid_kernel<<<ntiles, 256, 0, stream>>>(
        gB, P[0][1], w2sT[0], bias2[0], w1T[1], yT, N_NODES);
    // ---- layer 1 ----
    gather64_kernel<<<ngather, 256, 0, stream>>>(yT, rowptr, eids, gB, N_NODES);
    fused_mid_kernel<<<ntiles, 256, 0, stream>>>(
        gB, P[1][1], w2sT[1], bias2[1], w1T[2], yT, N_NODES);
    // ---- layer 2 ----
    gather64_kernel<<<ngather, 256, 0, stream>>>(yT, rowptr, eids, gB, N_NODES);
    fused_final_kernel<<<ntiles, 256, 0, stream>>>(
        gB, P[2][1], w2sT[2], bias2[2], h2, N_NODES);

    // ---- global mean pool ----
    hipMemsetAsync(sums, 0, (size_t)(N_GRAPHS * 96) * sizeof(float), stream);
    pool_seg_kernel<<<N_GRAPHS * POOL_SPLIT, 192, 0, stream>>>(h2, gstart, sums);
    finalize_kernel<<<cdiv_l(N_GRAPHS * 96, B), B, 0, stream>>>(
        sums, gstart, (float*)d_out);
}